// Round 9
// baseline (29.626 us; speedup 1.0000x reference)
//
#include <hip/hip_runtime.h>

#define G_     8
#define D_     144
#define O_     32
#define BATCH_ 8
#define KDIM_  (D_*G_)            // 1152
#define NPIX_  (BATCH_*64*64)     // 32768
#define KC_    36                 // K chunks of 32
#define NMAIN_ 512                // main blocks (64 px each)

typedef float  f32x4   __attribute__((ext_vector_type(4)));
typedef short  short8v __attribute__((ext_vector_type(8)));
typedef unsigned short ushort4v __attribute__((ext_vector_type(4)));

// ws layout:
//   [0, 73728)           Bpack: ushort[36][2][64][8]  bf16 B-fragments
//   [73728, 204800)      part:  float[512][64]
//   [204800, 8593424)    Xb:    uint4[524289]  per-input-pixel basis (8 bf16)
//                        slot 524288 = basis(0) for padding redirect
#define PART_OFF 73728
#define XB_OFF   204800
#define XB_CONST 524288

__device__ __forceinline__ unsigned int pack2bf(float a, float b) {
    unsigned int ua = __float_as_uint(a) + 0x8000u;
    unsigned int ub = __float_as_uint(b) + 0x8000u;
    return __builtin_amdgcn_perm(ub, ua, 0x07060302u);   // {hi16(ub),hi16(ua)}
}

__device__ __forceinline__ uint4 basis8(float pv) {
    constexpr float A_S = 2.1019642153762871f;   // sqrt(log2 e) * 7/4
    float e[G_];
#pragma unroll
    for (int g = 0; g < G_; ++g) {
        float gv = -2.0f + (float)g * (4.0f / 7.0f);
        float r  = fmaf(pv, A_S, -gv * A_S);
        e[g] = __builtin_amdgcn_exp2f(-(r * r));
    }
    uint4 au;
    au.x = pack2bf(e[0], e[1]);
    au.y = pack2bf(e[2], e[3]);
    au.z = pack2bf(e[4], e[5]);
    au.w = pack2bf(e[6], e[7]);
    return au;
}

// ---------- prep: blocks 0-575 Wsum->B-frags (16-way); 576+ basis ----------
__global__ void __launch_bounds__(256)
prep_kernel(const float* __restrict__ W, const float* __restrict__ x,
            unsigned short* __restrict__ Bpack, uint4* __restrict__ Xb) {
    int bid = blockIdx.x;
    if (bid < 576) {
        int t  = bid * 256 + threadIdx.x;     // 147456 threads
        int s  = t & 15;                      // d-split (9 d's each)
        int pr = t >> 4;                      // (o, k4)
        int o  = pr / (KDIM_ / 4);
        int k4 = pr - o * (KDIM_ / 4);
        const float4* p = reinterpret_cast<const float4*>(
            W + (size_t)o * (D_ * KDIM_) + (size_t)(s * 9) * KDIM_) + k4;
        float4 a = make_float4(0.f, 0.f, 0.f, 0.f);
#pragma unroll
        for (int dd = 0; dd < 9; ++dd) {
            float4 v = p[dd * (KDIM_ / 4)];
            a.x += v.x; a.y += v.y; a.z += v.z; a.w += v.w;
        }
#pragma unroll
        for (int sh = 1; sh <= 8; sh <<= 1) {
            a.x += __shfl_xor(a.x, sh); a.y += __shfl_xor(a.y, sh);
            a.z += __shfl_xor(a.z, sh); a.w += __shfl_xor(a.w, sh);
        }
        if (s == 0) {
            float v[4] = {a.x, a.y, a.z, a.w};
            ushort4v hb;
#pragma unroll
            for (int j = 0; j < 4; ++j) {
                unsigned int u = __float_as_uint(v[j]);
                u += 0x7FFFu + ((u >> 16) & 1u);          // RNE to bf16
                hb[j] = (unsigned short)(u >> 16);
            }
            int k  = k4 * 4;
            int kc = k >> 5;
            int lane_ = (((k >> 3) & 3) << 4) | (o & 15);
            int hh = o >> 4, e = k & 7;
            *reinterpret_cast<ushort4v*>(
                &Bpack[(((kc * 2 + hh) * 64) + lane_) * 8 + e]) = hb;
        }
    } else {
        int pi = (bid - 576) * 256 + threadIdx.x;    // 524288 input pixels
        Xb[pi] = basis8(x[pi]);
        if (pi == 0) Xb[XB_CONST] = basis8(0.0f);    // padding constant
    }
}

// ---------- main: MFMA GEMM; A from Xb (L2), B from Bpack (L2) ----------
__global__ void __launch_bounds__(256, 4)
main_kernel(const uint4* __restrict__ Xb, const uint4* __restrict__ Bg,
            float* __restrict__ out, float* __restrict__ part) {
    __shared__ float red[4 * 64];

    int tid  = threadIdx.x;
    int l    = tid & 63;
    int wv   = tid >> 6;         // 0..3
    int m    = l & 15;
    int hi   = l >> 4;
    int pixbase = blockIdx.x * 64 + wv * 16;
    int n    = pixbase + m;
    int b    = n >> 12;
    int y    = (n >> 6) & 63;
    int xc   = n & 63;

    // prologue: 36 A-frag indices (OOB -> basis(0) slot)
    int off[KC_];
#pragma unroll
    for (int kc = 0; kc < KC_; ++kc) {
        int d  = kc * 4 + hi;
        int c  = (d * 57) >> 9;          // d/9
        int r9 = d - c * 9;
        int kh = (r9 * 11) >> 5;         // r9/3
        int kw = r9 - kh * 3;
        int iy = y + kh - 1;
        int ix = xc + kw - 1;
        bool valid = ((unsigned)iy < 64u) & ((unsigned)ix < 64u);
        int pix = ((b * 16 + c) << 12) + (iy << 6) + ix;
        off[kc] = valid ? pix : XB_CONST;
    }

    f32x4 acc0 = {0.f, 0.f, 0.f, 0.f};
    f32x4 acc1 = {0.f, 0.f, 0.f, 0.f};

#pragma unroll
    for (int kc = 0; kc < KC_; ++kc) {
        uint4 au  = Xb[off[kc]];
        uint4 bu0 = Bg[(kc * 2 + 0) * 64 + l];
        uint4 bu1 = Bg[(kc * 2 + 1) * 64 + l];
        short8v afrag = __builtin_bit_cast(short8v, au);
        short8v b0 = __builtin_bit_cast(short8v, bu0);
        short8v b1 = __builtin_bit_cast(short8v, bu1);
        acc0 = __builtin_amdgcn_mfma_f32_16x16x32_bf16(afrag, b0, acc0, 0, 0, 0);
        acc1 = __builtin_amdgcn_mfma_f32_16x16x32_bf16(afrag, b1, acc1, 0, 0, 0);
    }

    // store raw GEMM result
    int prp = (pixbase & 4095) + hi * 4;
    float* dst0 = out + (((size_t)(b * O_ + m)) << 12) + prp;
    float* dst1 = out + (((size_t)(b * O_ + m + 16)) << 12) + prp;
    *reinterpret_cast<f32x4*>(dst0) = acc0;
    *reinterpret_cast<f32x4*>(dst1) = acc1;

    // BN partials from registers
    float s0 = acc0.x + acc0.y + acc0.z + acc0.w;
    float q0 = acc0.x*acc0.x + acc0.y*acc0.y + acc0.z*acc0.z + acc0.w*acc0.w;
    float s1 = acc1.x + acc1.y + acc1.z + acc1.w;
    float q1 = acc1.x*acc1.x + acc1.y*acc1.y + acc1.z*acc1.z + acc1.w*acc1.w;
    s0 += __shfl_xor(s0, 16); s0 += __shfl_xor(s0, 32);
    q0 += __shfl_xor(q0, 16); q0 += __shfl_xor(q0, 32);
    s1 += __shfl_xor(s1, 16); s1 += __shfl_xor(s1, 32);
    q1 += __shfl_xor(q1, 16); q1 += __shfl_xor(q1, 32);

    if (l < 16) {
        red[wv * 64 +      m] = s0;
        red[wv * 64 + 16 + m] = s1;
        red[wv * 64 + 32 + m] = q0;
        red[wv * 64 + 48 + m] = q1;
    }
    __syncthreads();
    if (tid < 64) {
        float v = 0.f;
#pragma unroll
        for (int w = 0; w < 4; ++w) v += red[w * 64 + tid];
        part[blockIdx.x * 64 + tid] = v;
    }
}

// ---------- BN apply: block bid owns plane bid; o = bid&31 uniform ----------
__global__ void __launch_bounds__(256)
bn_apply(float* __restrict__ out, const float* __restrict__ part,
         const float* __restrict__ gamma, const float* __restrict__ beta) {
    __shared__ float red[256 + 64];
    int tid = threadIdx.x;
    int ch  = tid & 63, grp = tid >> 6;
    float a = 0.f;
#pragma unroll 8
    for (int i = 0; i < 128; ++i)
        a += part[(grp * 128 + i) * 64 + ch];
    red[grp * 64 + ch] = a;
    __syncthreads();
    if (tid < 64)
        red[256 + tid] = red[tid] + red[64 + tid] + red[128 + tid] + red[192 + tid];
    __syncthreads();

    int o = blockIdx.x & 31;
    float S = red[256 + o], Q = red[256 + 32 + o];
    float mean = S * (1.f / (float)NPIX_);
    float var  = Q * (1.f / (float)NPIX_) - mean * mean;
    float rstd = rsqrtf(var + 1e-5f);
    float sc   = gamma[o] * rstd;
    float sh   = beta[o] - mean * sc;

    float4* f4 = reinterpret_cast<float4*>(out) + (size_t)blockIdx.x * 1024;
#pragma unroll
    for (int j = 0; j < 4; ++j) {
        float4 v = f4[tid + j * 256];
        v.x = v.x * sc + sh; v.y = v.y * sc + sh;
        v.z = v.z * sc + sh; v.w = v.w * sc + sh;
        f4[tid + j * 256] = v;
    }
}

extern "C" void kernel_launch(void* const* d_in, const int* in_sizes, int n_in,
                              void* d_out, int out_size, void* d_ws, size_t ws_size,
                              hipStream_t stream) {
    const float* x     = (const float*)d_in[0];
    const float* W     = (const float*)d_in[1];
    const float* gamma = (const float*)d_in[2];
    const float* beta  = (const float*)d_in[3];
    float* out = (float*)d_out;
    unsigned short* Bpack = (unsigned short*)d_ws;
    float* part = (float*)((char*)d_ws + PART_OFF);
    uint4* Xb   = (uint4*)((char*)d_ws + XB_OFF);

    hipLaunchKernelGGL(prep_kernel, dim3(576 + 2048), dim3(256), 0, stream,
                       W, x, Bpack, Xb);
    hipLaunchKernelGGL(main_kernel, dim3(NMAIN_), dim3(256), 0, stream,
                       Xb, (const uint4*)Bpack, out, part);
    hipLaunchKernelGGL(bn_apply, dim3(256), dim3(256), 0, stream,
                       out, part, gamma, beta);
}

// Round 10
// 26.844 us; speedup vs baseline: 1.1036x; 1.1036x over previous
//
#include <hip/hip_runtime.h>

#define G_     8
#define D_     144
#define O_     32
#define BATCH_ 8
#define KDIM_  (D_*G_)            // 1152
#define NPIX_  (BATCH_*64*64)     // 32768
#define KC_    36                 // K chunks of 32
#define NMAIN_ 512                // main blocks (64 px each)

typedef float  f32x4   __attribute__((ext_vector_type(4)));
typedef short  short8v __attribute__((ext_vector_type(8)));
typedef unsigned short ushort4v __attribute__((ext_vector_type(4)));

// ws layout:
//   [0, 73728)           Bpack: ushort[36][2][64][8]  bf16 B-fragments
//   [73728, 204800)      part:  float[512][64]
//   [204800, 8593424)    Xb:    uint4[524289]  per-input-pixel basis (8 bf16)
//                        slot 524288 = basis(0) for padding redirect
#define PART_OFF 73728
#define XB_OFF   204800
#define XB_CONST 524288

__device__ __forceinline__ unsigned int pack2bf(float a, float b) {
    unsigned int ua = __float_as_uint(a) + 0x8000u;
    unsigned int ub = __float_as_uint(b) + 0x8000u;
    return __builtin_amdgcn_perm(ub, ua, 0x07060302u);   // {hi16(ub),hi16(ua)}
}

__device__ __forceinline__ uint4 basis8(float pv) {
    constexpr float A_S = 2.1019642153762871f;   // sqrt(log2 e) * 7/4
    float e[G_];
#pragma unroll
    for (int g = 0; g < G_; ++g) {
        float gv = -2.0f + (float)g * (4.0f / 7.0f);
        float r  = fmaf(pv, A_S, -gv * A_S);
        e[g] = __builtin_amdgcn_exp2f(-(r * r));
    }
    uint4 au;
    au.x = pack2bf(e[0], e[1]);
    au.y = pack2bf(e[2], e[3]);
    au.z = pack2bf(e[4], e[5]);
    au.w = pack2bf(e[6], e[7]);
    return au;
}

// ---------- prep ----------
// blocks 0-143: Wsum -> B-frags, COALESCED: lane = (s<<4)|k4lo, so each
//   16-lane group reads 16 consecutive float4 (256B segment); 4-way d-split
//   combined in-wave via shfl_xor(16|32). W fetched exactly once (21.6MB).
// blocks 144+: per-input-pixel RBF basis -> Xb
__global__ void __launch_bounds__(256)
prep_kernel(const float* __restrict__ W, const float* __restrict__ x,
            unsigned short* __restrict__ Bpack, uint4* __restrict__ Xb) {
    int bid = blockIdx.x;
    if (bid < 144) {
        int tid  = threadIdx.x;
        int k4lo = tid & 15;
        int s    = (tid >> 4) & 3;           // d-split 0..3 (36 d's each)
        int grp  = tid >> 6;                 // wave id 0..3
        int pairid = bid * 64 + grp * 16 + k4lo;   // (o,k4) pair, 9216 total
        int o  = pairid / 288;
        int k4 = pairid - o * 288;
        const float4* p = reinterpret_cast<const float4*>(
            W + (size_t)o * (D_ * KDIM_) + (size_t)(s * 36) * KDIM_) + k4;
        float4 a = make_float4(0.f, 0.f, 0.f, 0.f);
#pragma unroll
        for (int dd = 0; dd < 36; ++dd) {
            float4 v = p[dd * (KDIM_ / 4)];
            a.x += v.x; a.y += v.y; a.z += v.z; a.w += v.w;
        }
        // combine 4 d-splits (lanes s<<4 apart) in-wave
        a.x += __shfl_xor(a.x, 16); a.y += __shfl_xor(a.y, 16);
        a.z += __shfl_xor(a.z, 16); a.w += __shfl_xor(a.w, 16);
        a.x += __shfl_xor(a.x, 32); a.y += __shfl_xor(a.y, 32);
        a.z += __shfl_xor(a.z, 32); a.w += __shfl_xor(a.w, 32);
        if (s == 0) {
            float v[4] = {a.x, a.y, a.z, a.w};
            ushort4v hb;
#pragma unroll
            for (int j = 0; j < 4; ++j) {
                unsigned int u = __float_as_uint(v[j]);
                u += 0x7FFFu + ((u >> 16) & 1u);          // RNE to bf16
                hb[j] = (unsigned short)(u >> 16);
            }
            int k  = k4 * 4;
            int kc = k >> 5;
            int lane_ = (((k >> 3) & 3) << 4) | (o & 15);
            int hh = o >> 4, e = k & 7;
            *reinterpret_cast<ushort4v*>(
                &Bpack[(((kc * 2 + hh) * 64) + lane_) * 8 + e]) = hb;
        }
    } else {
        int pi = (bid - 144) * 256 + threadIdx.x;    // 524288 input pixels
        Xb[pi] = basis8(x[pi]);
        if (pi == 0) Xb[XB_CONST] = basis8(0.0f);    // padding constant
    }
}

// ---------- main: MFMA GEMM; A gathered from Xb, B staged in LDS ----------
__global__ void __launch_bounds__(256, 2)
main_kernel(const uint4* __restrict__ Xb, const uint4* __restrict__ Bpackv,
            float* __restrict__ out, float* __restrict__ part) {
    __shared__ uint4 Bsh[KC_ * 2 * 64];          // 73728 B; reused for reduce

#pragma unroll
    for (int i = 0; i < 18; ++i) {
        int idx = threadIdx.x + i * 256;
        Bsh[idx] = Bpackv[idx];
    }

    int tid  = threadIdx.x;
    int l    = tid & 63;
    int wv   = tid >> 6;         // 0..3
    int m    = l & 15;
    int hi   = l >> 4;
    int pixbase = blockIdx.x * 64 + wv * 16;
    int n    = pixbase + m;
    int b    = n >> 12;
    int y    = (n >> 6) & 63;
    int xc   = n & 63;

    // prologue: 36 A-frag indices (OOB -> basis(0) slot)
    int off[KC_];
#pragma unroll
    for (int kc = 0; kc < KC_; ++kc) {
        int d  = kc * 4 + hi;
        int c  = (d * 57) >> 9;          // d/9
        int r9 = d - c * 9;
        int kh = (r9 * 11) >> 5;         // r9/3
        int kw = r9 - kh * 3;
        int iy = y + kh - 1;
        int ix = xc + kw - 1;
        bool valid = ((unsigned)iy < 64u) & ((unsigned)ix < 64u);
        int pix = ((b * 16 + c) << 12) + (iy << 6) + ix;
        off[kc] = valid ? pix : XB_CONST;
    }
    __syncthreads();                     // B staged

    f32x4 acc0 = {0.f, 0.f, 0.f, 0.f};
    f32x4 acc1 = {0.f, 0.f, 0.f, 0.f};

#pragma unroll
    for (int kc = 0; kc < KC_; ++kc) {
        uint4 au = Xb[off[kc]];
        short8v afrag = __builtin_bit_cast(short8v, au);
        short8v b0 = __builtin_bit_cast(short8v, Bsh[(kc * 2 + 0) * 64 + l]);
        short8v b1 = __builtin_bit_cast(short8v, Bsh[(kc * 2 + 1) * 64 + l]);
        acc0 = __builtin_amdgcn_mfma_f32_16x16x32_bf16(afrag, b0, acc0, 0, 0, 0);
        acc1 = __builtin_amdgcn_mfma_f32_16x16x32_bf16(afrag, b1, acc1, 0, 0, 0);
    }

    // store raw GEMM result
    int prp = (pixbase & 4095) + hi * 4;
    float* dst0 = out + (((size_t)(b * O_ + m)) << 12) + prp;
    float* dst1 = out + (((size_t)(b * O_ + m + 16)) << 12) + prp;
    *reinterpret_cast<f32x4*>(dst0) = acc0;
    *reinterpret_cast<f32x4*>(dst1) = acc1;

    // BN partials from registers
    float s0 = acc0.x + acc0.y + acc0.z + acc0.w;
    float q0 = acc0.x*acc0.x + acc0.y*acc0.y + acc0.z*acc0.z + acc0.w*acc0.w;
    float s1 = acc1.x + acc1.y + acc1.z + acc1.w;
    float q1 = acc1.x*acc1.x + acc1.y*acc1.y + acc1.z*acc1.z + acc1.w*acc1.w;
    s0 += __shfl_xor(s0, 16); s0 += __shfl_xor(s0, 32);
    q0 += __shfl_xor(q0, 16); q0 += __shfl_xor(q0, 32);
    s1 += __shfl_xor(s1, 16); s1 += __shfl_xor(s1, 32);
    q1 += __shfl_xor(q1, 16); q1 += __shfl_xor(q1, 32);

    float* red = (float*)Bsh;
    __syncthreads();                     // done reading Bsh
    if (l < 16) {
        red[wv * 64 +      m] = s0;
        red[wv * 64 + 16 + m] = s1;
        red[wv * 64 + 32 + m] = q0;
        red[wv * 64 + 48 + m] = q1;
    }
    __syncthreads();
    if (tid < 64) {
        float v = 0.f;
#pragma unroll
        for (int w = 0; w < 4; ++w) v += red[w * 64 + tid];
        part[blockIdx.x * 64 + tid] = v;
    }
}

// ---------- BN apply: block bid owns plane bid; o = bid&31 uniform ----------
__global__ void __launch_bounds__(256)
bn_apply(float* __restrict__ out, const float* __restrict__ part,
         const float* __restrict__ gamma, const float* __restrict__ beta) {
    __shared__ float red[256 + 64];
    int tid = threadIdx.x;
    int ch  = tid & 63, grp = tid >> 6;
    float a = 0.f;
#pragma unroll 8
    for (int i = 0; i < 128; ++i)
        a += part[(grp * 128 + i) * 64 + ch];
    red[grp * 64 + ch] = a;
    __syncthreads();
    if (tid < 64)
        red[256 + tid] = red[tid] + red[64 + tid] + red[128 + tid] + red[192 + tid];
    __syncthreads();

    int o = blockIdx.x & 31;
    float S = red[256 + o], Q = red[256 + 32 + o];
    float mean = S * (1.f / (float)NPIX_);
    float var  = Q * (1.f / (float)NPIX_) - mean * mean;
    float rstd = rsqrtf(var + 1e-5f);
    float sc   = gamma[o] * rstd;
    float sh   = beta[o] - mean * sc;

    float4* f4 = reinterpret_cast<float4*>(out) + (size_t)blockIdx.x * 1024;
#pragma unroll
    for (int j = 0; j < 4; ++j) {
        float4 v = f4[tid + j * 256];
        v.x = v.x * sc + sh; v.y = v.y * sc + sh;
        v.z = v.z * sc + sh; v.w = v.w * sc + sh;
        f4[tid + j * 256] = v;
    }
}

extern "C" void kernel_launch(void* const* d_in, const int* in_sizes, int n_in,
                              void* d_out, int out_size, void* d_ws, size_t ws_size,
                              hipStream_t stream) {
    const float* x     = (const float*)d_in[0];
    const float* W     = (const float*)d_in[1];
    const float* gamma = (const float*)d_in[2];
    const float* beta  = (const float*)d_in[3];
    float* out = (float*)d_out;
    unsigned short* Bpack = (unsigned short*)d_ws;
    float* part = (float*)((char*)d_ws + PART_OFF);
    uint4* Xb   = (uint4*)((char*)d_ws + XB_OFF);

    hipLaunchKernelGGL(prep_kernel, dim3(144 + 2048), dim3(256), 0, stream,
                       W, x, Bpack, Xb);
    hipLaunchKernelGGL(main_kernel, dim3(NMAIN_), dim3(256), 0, stream,
                       Xb, (const uint4*)Bpack, out, part);
    hipLaunchKernelGGL(bn_apply, dim3(256), dim3(256), 0, stream,
                       out, part, gamma, beta);
}

// Round 11
// 25.607 us; speedup vs baseline: 1.1569x; 1.0483x over previous
//
#include <hip/hip_runtime.h>

#define G_     8
#define D_     144
#define O_     32
#define BATCH_ 8
#define KDIM_  (D_*G_)            // 1152
#define NPIX_  (BATCH_*64*64)     // 32768
#define KC_    36                 // K chunks of 32
#define NMAIN_ 512                // main blocks (64 px each)

typedef float  f32x4   __attribute__((ext_vector_type(4)));
typedef short  short8v __attribute__((ext_vector_type(8)));
typedef unsigned short ushort4v __attribute__((ext_vector_type(4)));

// ws layout:
//   [0, 73728)           Bpack: ushort[36][2][64][8]  bf16 B-fragments
//   [73728, 204800)      part:  float[512][64]
//   [204800, 8593424)    Xb:    uint4[524289]  per-input-pixel basis (8 bf16)
//                        slot 524288 = basis(0) for padding redirect
#define PART_OFF 73728
#define XB_OFF   204800
#define XB_CONST 524288

__device__ __forceinline__ unsigned int pack2bf(float a, float b) {
    unsigned int ua = __float_as_uint(a) + 0x8000u;
    unsigned int ub = __float_as_uint(b) + 0x8000u;
    return __builtin_amdgcn_perm(ub, ua, 0x07060302u);   // {hi16(ub),hi16(ua)}
}

__device__ __forceinline__ uint4 basis8(float pv) {
    constexpr float A_S = 2.1019642153762871f;   // sqrt(log2 e) * 7/4
    float e[G_];
#pragma unroll
    for (int g = 0; g < G_; ++g) {
        float gv = -2.0f + (float)g * (4.0f / 7.0f);
        float r  = fmaf(pv, A_S, -gv * A_S);
        e[g] = __builtin_amdgcn_exp2f(-(r * r));
    }
    uint4 au;
    au.x = pack2bf(e[0], e[1]);
    au.y = pack2bf(e[2], e[3]);
    au.z = pack2bf(e[4], e[5]);
    au.w = pack2bf(e[6], e[7]);
    return au;
}

// ---------- prep ----------
// blocks 0-143: Wsum -> B-frags, coalesced (R10 layout).
// blocks 144+: per-input-pixel RBF basis -> Xb
__global__ void __launch_bounds__(256)
prep_kernel(const float* __restrict__ W, const float* __restrict__ x,
            unsigned short* __restrict__ Bpack, uint4* __restrict__ Xb) {
    int bid = blockIdx.x;
    if (bid < 144) {
        int tid  = threadIdx.x;
        int k4lo = tid & 15;
        int s    = (tid >> 4) & 3;           // d-split 0..3 (36 d's each)
        int grp  = tid >> 6;                 // wave id 0..3
        int pairid = bid * 64 + grp * 16 + k4lo;   // (o,k4) pair, 9216 total
        int o  = pairid / 288;
        int k4 = pairid - o * 288;
        const float4* p = reinterpret_cast<const float4*>(
            W + (size_t)o * (D_ * KDIM_) + (size_t)(s * 36) * KDIM_) + k4;
        float4 a = make_float4(0.f, 0.f, 0.f, 0.f);
#pragma unroll
        for (int dd = 0; dd < 36; ++dd) {
            float4 v = p[dd * (KDIM_ / 4)];
            a.x += v.x; a.y += v.y; a.z += v.z; a.w += v.w;
        }
        a.x += __shfl_xor(a.x, 16); a.y += __shfl_xor(a.y, 16);
        a.z += __shfl_xor(a.z, 16); a.w += __shfl_xor(a.w, 16);
        a.x += __shfl_xor(a.x, 32); a.y += __shfl_xor(a.y, 32);
        a.z += __shfl_xor(a.z, 32); a.w += __shfl_xor(a.w, 32);
        if (s == 0) {
            float v[4] = {a.x, a.y, a.z, a.w};
            ushort4v hb;
#pragma unroll
            for (int j = 0; j < 4; ++j) {
                unsigned int u = __float_as_uint(v[j]);
                u += 0x7FFFu + ((u >> 16) & 1u);          // RNE to bf16
                hb[j] = (unsigned short)(u >> 16);
            }
            int k  = k4 * 4;
            int kc = k >> 5;
            int lane_ = (((k >> 3) & 3) << 4) | (o & 15);
            int hh = o >> 4, e = k & 7;
            *reinterpret_cast<ushort4v*>(
                &Bpack[(((kc * 2 + hh) * 64) + lane_) * 8 + e]) = hb;
        }
    } else {
        int pi = (bid - 144) * 256 + threadIdx.x;    // 524288 input pixels
        Xb[pi] = basis8(x[pi]);
        if (pi == 0) Xb[XB_CONST] = basis8(0.0f);    // padding constant
    }
}

// ---------- main: MFMA GEMM; A gathered from Xb (L2), B staged in LDS ----------
// T1 XCD swizzle: vb = (bid&7)*64 + (bid>>3). XCD k (blocks with bid%8==k)
// then owns batch k exclusively -> per-XCD Xb working set = 1.05MB, L2-fit.
__global__ void __launch_bounds__(256, 2)
main_kernel(const uint4* __restrict__ Xb, const uint4* __restrict__ Bpackv,
            float* __restrict__ out, float* __restrict__ part) {
    __shared__ uint4 Bsh[KC_ * 2 * 64];          // 73728 B; reused for reduce

#pragma unroll
    for (int i = 0; i < 18; ++i) {
        int idx = threadIdx.x + i * 256;
        Bsh[idx] = Bpackv[idx];
    }

    int vb   = ((blockIdx.x & 7) << 6) | (blockIdx.x >> 3);   // XCD-local batch
    int tid  = threadIdx.x;
    int l    = tid & 63;
    int wv   = tid >> 6;         // 0..3
    int m    = l & 15;
    int hi   = l >> 4;
    int pixbase = vb * 64 + wv * 16;
    int n    = pixbase + m;
    int b    = n >> 12;
    int y    = (n >> 6) & 63;
    int xc   = n & 63;

    // prologue: 36 A-frag indices (OOB -> basis(0) slot)
    int off[KC_];
#pragma unroll
    for (int kc = 0; kc < KC_; ++kc) {
        int d  = kc * 4 + hi;
        int c  = (d * 57) >> 9;          // d/9
        int r9 = d - c * 9;
        int kh = (r9 * 11) >> 5;         // r9/3
        int kw = r9 - kh * 3;
        int iy = y + kh - 1;
        int ix = xc + kw - 1;
        bool valid = ((unsigned)iy < 64u) & ((unsigned)ix < 64u);
        int pix = ((b * 16 + c) << 12) + (iy << 6) + ix;
        off[kc] = valid ? pix : XB_CONST;
    }
    __syncthreads();                     // B staged

    f32x4 acc0 = {0.f, 0.f, 0.f, 0.f};
    f32x4 acc1 = {0.f, 0.f, 0.f, 0.f};

#pragma unroll
    for (int kc = 0; kc < KC_; ++kc) {
        uint4 au = Xb[off[kc]];
        short8v afrag = __builtin_bit_cast(short8v, au);
        short8v b0 = __builtin_bit_cast(short8v, Bsh[(kc * 2 + 0) * 64 + l]);
        short8v b1 = __builtin_bit_cast(short8v, Bsh[(kc * 2 + 1) * 64 + l]);
        acc0 = __builtin_amdgcn_mfma_f32_16x16x32_bf16(afrag, b0, acc0, 0, 0, 0);
        acc1 = __builtin_amdgcn_mfma_f32_16x16x32_bf16(afrag, b1, acc1, 0, 0, 0);
    }

    // store raw GEMM result
    int prp = (pixbase & 4095) + hi * 4;
    float* dst0 = out + (((size_t)(b * O_ + m)) << 12) + prp;
    float* dst1 = out + (((size_t)(b * O_ + m + 16)) << 12) + prp;
    *reinterpret_cast<f32x4*>(dst0) = acc0;
    *reinterpret_cast<f32x4*>(dst1) = acc1;

    // BN partials from registers
    float s0 = acc0.x + acc0.y + acc0.z + acc0.w;
    float q0 = acc0.x*acc0.x + acc0.y*acc0.y + acc0.z*acc0.z + acc0.w*acc0.w;
    float s1 = acc1.x + acc1.y + acc1.z + acc1.w;
    float q1 = acc1.x*acc1.x + acc1.y*acc1.y + acc1.z*acc1.z + acc1.w*acc1.w;
    s0 += __shfl_xor(s0, 16); s0 += __shfl_xor(s0, 32);
    q0 += __shfl_xor(q0, 16); q0 += __shfl_xor(q0, 32);
    s1 += __shfl_xor(s1, 16); s1 += __shfl_xor(s1, 32);
    q1 += __shfl_xor(q1, 16); q1 += __shfl_xor(q1, 32);

    float* red = (float*)Bsh;
    __syncthreads();                     // done reading Bsh
    if (l < 16) {
        red[wv * 64 +      m] = s0;
        red[wv * 64 + 16 + m] = s1;
        red[wv * 64 + 32 + m] = q0;
        red[wv * 64 + 48 + m] = q1;
    }
    __syncthreads();
    if (tid < 64) {
        float v = 0.f;
#pragma unroll
        for (int w = 0; w < 4; ++w) v += red[w * 64 + tid];
        part[vb * 64 + tid] = v;
    }
}

// ---------- BN apply: block bid owns plane bid; o = bid&31 uniform ----------
__global__ void __launch_bounds__(256)
bn_apply(float* __restrict__ out, const float* __restrict__ part,
         const float* __restrict__ gamma, const float* __restrict__ beta) {
    __shared__ float red[256 + 64];
    int tid = threadIdx.x;
    int ch  = tid & 63, grp = tid >> 6;
    float a = 0.f;
#pragma unroll 8
    for (int i = 0; i < 128; ++i)
        a += part[(grp * 128 + i) * 64 + ch];
    red[grp * 64 + ch] = a;
    __syncthreads();
    if (tid < 64)
        red[256 + tid] = red[tid] + red[64 + tid] + red[128 + tid] + red[192 + tid];
    __syncthreads();

    int o = blockIdx.x & 31;
    float S = red[256 + o], Q = red[256 + 32 + o];
    float mean = S * (1.f / (float)NPIX_);
    float var  = Q * (1.f / (float)NPIX_) - mean * mean;
    float rstd = rsqrtf(var + 1e-5f);
    float sc   = gamma[o] * rstd;
    float sh   = beta[o] - mean * sc;

    float4* f4 = reinterpret_cast<float4*>(out) + (size_t)blockIdx.x * 1024;
#pragma unroll
    for (int j = 0; j < 4; ++j) {
        float4 v = f4[tid + j * 256];
        v.x = v.x * sc + sh; v.y = v.y * sc + sh;
        v.z = v.z * sc + sh; v.w = v.w * sc + sh;
        f4[tid + j * 256] = v;
    }
}

extern "C" void kernel_launch(void* const* d_in, const int* in_sizes, int n_in,
                              void* d_out, int out_size, void* d_ws, size_t ws_size,
                              hipStream_t stream) {
    const float* x     = (const float*)d_in[0];
    const float* W     = (const float*)d_in[1];
    const float* gamma = (const float*)d_in[2];
    const float* beta  = (const float*)d_in[3];
    float* out = (float*)d_out;
    unsigned short* Bpack = (unsigned short*)d_ws;
    float* part = (float*)((char*)d_ws + PART_OFF);
    uint4* Xb   = (uint4*)((char*)d_ws + XB_OFF);

    hipLaunchKernelGGL(prep_kernel, dim3(144 + 2048), dim3(256), 0, stream,
                       W, x, Bpack, Xb);
    hipLaunchKernelGGL(main_kernel, dim3(NMAIN_), dim3(256), 0, stream,
                       Xb, (const uint4*)Bpack, out, part);
    hipLaunchKernelGGL(bn_apply, dim3(256), dim3(256), 0, stream,
                       out, part, gamma, beta);
}

// Round 12
// 23.631 us; speedup vs baseline: 1.2537x; 1.0836x over previous
//
#include <hip/hip_runtime.h>

#define G_     8
#define D_     144
#define O_     32
#define BATCH_ 8
#define KDIM_  (D_*G_)            // 1152
#define NPIX_  (BATCH_*64*64)     // 32768
#define KC_    36                 // K chunks of 32
#define NMAIN_ 512                // main blocks (64 px each)

typedef float  f32x4   __attribute__((ext_vector_type(4)));
typedef short  short8v __attribute__((ext_vector_type(8)));
typedef unsigned short ushort4v __attribute__((ext_vector_type(4)));

// ws layout:
//   [0, 73728)           Bpack: ushort[36][2][64][8]  bf16 B-fragments
//   [73728, 204800)      part:  float[512][64]
//   [204800, 8593424)    Xb:    uint4[524289]  per-input-pixel basis (8 bf16)
//                        slot 524288 = basis(0) for padding redirect
#define PART_OFF 73728
#define XB_OFF   204800
#define XB_CONST 524288

__device__ __forceinline__ unsigned int pack2bf(float a, float b) {
    unsigned int ua = __float_as_uint(a) + 0x8000u;
    unsigned int ub = __float_as_uint(b) + 0x8000u;
    return __builtin_amdgcn_perm(ub, ua, 0x07060302u);   // {hi16(ub),hi16(ua)}
}

__device__ __forceinline__ uint4 basis8(float pv) {
    constexpr float A_S = 2.1019642153762871f;   // sqrt(log2 e) * 7/4
    float e[G_];
#pragma unroll
    for (int g = 0; g < G_; ++g) {
        float gv = -2.0f + (float)g * (4.0f / 7.0f);
        float r  = fmaf(pv, A_S, -gv * A_S);
        e[g] = __builtin_amdgcn_exp2f(-(r * r));
    }
    uint4 au;
    au.x = pack2bf(e[0], e[1]);
    au.y = pack2bf(e[2], e[3]);
    au.z = pack2bf(e[4], e[5]);
    au.w = pack2bf(e[6], e[7]);
    return au;
}

// ---------- prep ----------
// blocks 0-143: Wsum -> B-frags, coalesced (R10 layout).
// blocks 144-655: basis, 4 px/thread via float4 x loads.
__global__ void __launch_bounds__(256)
prep_kernel(const float* __restrict__ W, const float* __restrict__ x,
            unsigned short* __restrict__ Bpack, uint4* __restrict__ Xb) {
    int bid = blockIdx.x;
    if (bid < 144) {
        int tid  = threadIdx.x;
        int k4lo = tid & 15;
        int s    = (tid >> 4) & 3;           // d-split 0..3 (36 d's each)
        int grp  = tid >> 6;                 // wave id 0..3
        int pairid = bid * 64 + grp * 16 + k4lo;   // (o,k4) pair, 9216 total
        int o  = pairid / 288;
        int k4 = pairid - o * 288;
        const float4* p = reinterpret_cast<const float4*>(
            W + (size_t)o * (D_ * KDIM_) + (size_t)(s * 36) * KDIM_) + k4;
        float4 a = make_float4(0.f, 0.f, 0.f, 0.f);
#pragma unroll
        for (int dd = 0; dd < 36; ++dd) {
            float4 v = p[dd * (KDIM_ / 4)];
            a.x += v.x; a.y += v.y; a.z += v.z; a.w += v.w;
        }
        a.x += __shfl_xor(a.x, 16); a.y += __shfl_xor(a.y, 16);
        a.z += __shfl_xor(a.z, 16); a.w += __shfl_xor(a.w, 16);
        a.x += __shfl_xor(a.x, 32); a.y += __shfl_xor(a.y, 32);
        a.z += __shfl_xor(a.z, 32); a.w += __shfl_xor(a.w, 32);
        if (s == 0) {
            float v[4] = {a.x, a.y, a.z, a.w};
            ushort4v hb;
#pragma unroll
            for (int j = 0; j < 4; ++j) {
                unsigned int u = __float_as_uint(v[j]);
                u += 0x7FFFu + ((u >> 16) & 1u);          // RNE to bf16
                hb[j] = (unsigned short)(u >> 16);
            }
            int k  = k4 * 4;
            int kc = k >> 5;
            int lane_ = (((k >> 3) & 3) << 4) | (o & 15);
            int hh = o >> 4, e = k & 7;
            *reinterpret_cast<ushort4v*>(
                &Bpack[(((kc * 2 + hh) * 64) + lane_) * 8 + e]) = hb;
        }
    } else {
        int pi4 = (bid - 144) * 256 + threadIdx.x;   // 131072 quads
        float4 xv = reinterpret_cast<const float4*>(x)[pi4];
        uint4* dst = Xb + (size_t)pi4 * 4;
        dst[0] = basis8(xv.x);
        dst[1] = basis8(xv.y);
        dst[2] = basis8(xv.z);
        dst[3] = basis8(xv.w);
        if (pi4 == 0) Xb[XB_CONST] = basis8(0.0f);   // padding constant
    }
}

// ---------- main: MFMA GEMM; A gathered from Xb (L2), B staged in LDS ----------
// T1 XCD swizzle: vb = (bid&7)*64 + (bid>>3) -> XCD k owns batch k (L2-fit).
__global__ void __launch_bounds__(256, 2)
main_kernel(const uint4* __restrict__ Xb, const uint4* __restrict__ Bpackv,
            float* __restrict__ out, float* __restrict__ part) {
    __shared__ uint4 Bsh[KC_ * 2 * 64];          // 73728 B; reused for reduce

#pragma unroll
    for (int i = 0; i < 18; ++i) {
        int idx = threadIdx.x + i * 256;
        Bsh[idx] = Bpackv[idx];
    }

    int vb   = ((blockIdx.x & 7) << 6) | (blockIdx.x >> 3);   // XCD-local batch
    int tid  = threadIdx.x;
    int l    = tid & 63;
    int wv   = tid >> 6;         // 0..3
    int m    = l & 15;
    int hi   = l >> 4;
    int pixbase = vb * 64 + wv * 16;
    int n    = pixbase + m;
    int b    = n >> 12;
    int y    = (n >> 6) & 63;
    int xc   = n & 63;

    // prologue: 36 A-frag indices (OOB -> basis(0) slot)
    int off[KC_];
#pragma unroll
    for (int kc = 0; kc < KC_; ++kc) {
        int d  = kc * 4 + hi;
        int c  = (d * 57) >> 9;          // d/9
        int r9 = d - c * 9;
        int kh = (r9 * 11) >> 5;         // r9/3
        int kw = r9 - kh * 3;
        int iy = y + kh - 1;
        int ix = xc + kw - 1;
        bool valid = ((unsigned)iy < 64u) & ((unsigned)ix < 64u);
        int pix = ((b * 16 + c) << 12) + (iy << 6) + ix;
        off[kc] = valid ? pix : XB_CONST;
    }
    __syncthreads();                     // B staged

    f32x4 acc0 = {0.f, 0.f, 0.f, 0.f};
    f32x4 acc1 = {0.f, 0.f, 0.f, 0.f};

#pragma unroll
    for (int kc = 0; kc < KC_; ++kc) {
        uint4 au = Xb[off[kc]];
        short8v afrag = __builtin_bit_cast(short8v, au);
        short8v b0 = __builtin_bit_cast(short8v, Bsh[(kc * 2 + 0) * 64 + l]);
        short8v b1 = __builtin_bit_cast(short8v, Bsh[(kc * 2 + 1) * 64 + l]);
        acc0 = __builtin_amdgcn_mfma_f32_16x16x32_bf16(afrag, b0, acc0, 0, 0, 0);
        acc1 = __builtin_amdgcn_mfma_f32_16x16x32_bf16(afrag, b1, acc1, 0, 0, 0);
    }

    // store raw GEMM result
    int prp = (pixbase & 4095) + hi * 4;
    float* dst0 = out + (((size_t)(b * O_ + m)) << 12) + prp;
    float* dst1 = out + (((size_t)(b * O_ + m + 16)) << 12) + prp;
    *reinterpret_cast<f32x4*>(dst0) = acc0;
    *reinterpret_cast<f32x4*>(dst1) = acc1;

    // BN partials from registers
    float s0 = acc0.x + acc0.y + acc0.z + acc0.w;
    float q0 = acc0.x*acc0.x + acc0.y*acc0.y + acc0.z*acc0.z + acc0.w*acc0.w;
    float s1 = acc1.x + acc1.y + acc1.z + acc1.w;
    float q1 = acc1.x*acc1.x + acc1.y*acc1.y + acc1.z*acc1.z + acc1.w*acc1.w;
    s0 += __shfl_xor(s0, 16); s0 += __shfl_xor(s0, 32);
    q0 += __shfl_xor(q0, 16); q0 += __shfl_xor(q0, 32);
    s1 += __shfl_xor(s1, 16); s1 += __shfl_xor(s1, 32);
    q1 += __shfl_xor(q1, 16); q1 += __shfl_xor(q1, 32);

    float* red = (float*)Bsh;
    __syncthreads();                     // done reading Bsh
    if (l < 16) {
        red[wv * 64 +      m] = s0;
        red[wv * 64 + 16 + m] = s1;
        red[wv * 64 + 32 + m] = q0;
        red[wv * 64 + 48 + m] = q1;
    }
    __syncthreads();
    if (tid < 64) {
        float v = 0.f;
#pragma unroll
        for (int w = 0; w < 4; ++w) v += red[w * 64 + tid];
        part[vb * 64 + tid] = v;
    }
}

// ---------- BN apply: column-only stat reduce (4KB/block, not 128KB) ----------
__global__ void __launch_bounds__(256)
bn_apply(float* __restrict__ out, const float* __restrict__ part,
         const float* __restrict__ gamma, const float* __restrict__ beta) {
    __shared__ float ws[8];
    int tid = threadIdx.x;
    int o   = blockIdx.x & 31;

    // reduce only columns o (sum) and 32+o (sumsq): 512 rows, 2 per thread
    float s = part[tid * 64 + o]      + part[(tid + 256) * 64 + o];
    float q = part[tid * 64 + 32 + o] + part[(tid + 256) * 64 + 32 + o];
#pragma unroll
    for (int off = 32; off > 0; off >>= 1) {
        s += __shfl_down(s, off);
        q += __shfl_down(q, off);
    }
    int wvid = tid >> 6;
    if ((tid & 63) == 0) { ws[wvid] = s; ws[4 + wvid] = q; }
    __syncthreads();
    float S = ws[0] + ws[1] + ws[2] + ws[3];
    float Q = ws[4] + ws[5] + ws[6] + ws[7];

    float mean = S * (1.f / (float)NPIX_);
    float var  = Q * (1.f / (float)NPIX_) - mean * mean;
    float rstd = rsqrtf(var + 1e-5f);
    float sc   = gamma[o] * rstd;
    float sh   = beta[o] - mean * sc;

    float4* f4 = reinterpret_cast<float4*>(out) + (size_t)blockIdx.x * 1024;
#pragma unroll
    for (int j = 0; j < 4; ++j) {
        float4 v = f4[tid + j * 256];
        v.x = v.x * sc + sh; v.y = v.y * sc + sh;
        v.z = v.z * sc + sh; v.w = v.w * sc + sh;
        f4[tid + j * 256] = v;
    }
}

extern "C" void kernel_launch(void* const* d_in, const int* in_sizes, int n_in,
                              void* d_out, int out_size, void* d_ws, size_t ws_size,
                              hipStream_t stream) {
    const float* x     = (const float*)d_in[0];
    const float* W     = (const float*)d_in[1];
    const float* gamma = (const float*)d_in[2];
    const float* beta  = (const float*)d_in[3];
    float* out = (float*)d_out;
    unsigned short* Bpack = (unsigned short*)d_ws;
    float* part = (float*)((char*)d_ws + PART_OFF);
    uint4* Xb   = (uint4*)((char*)d_ws + XB_OFF);

    hipLaunchKernelGGL(prep_kernel, dim3(144 + 512), dim3(256), 0, stream,
                       W, x, Bpack, Xb);
    hipLaunchKernelGGL(main_kernel, dim3(NMAIN_), dim3(256), 0, stream,
                       Xb, (const uint4*)Bpack, out, part);
    hipLaunchKernelGGL(bn_apply, dim3(256), dim3(256), 0, stream,
                       out, part, gamma, beta);
}

// Round 13
// 22.594 us; speedup vs baseline: 1.3112x; 1.0459x over previous
//
#include <hip/hip_runtime.h>

#define G_     8
#define D_     144
#define O_     32
#define BATCH_ 8
#define KDIM_  (D_*G_)            // 1152
#define NPIX_  (BATCH_*64*64)     // 32768
#define KC_    36                 // K chunks of 32
#define NMAIN_ 256                // main blocks (128 px each)

typedef float  f32x4   __attribute__((ext_vector_type(4)));
typedef short  short8v __attribute__((ext_vector_type(8)));
typedef unsigned short ushort4v __attribute__((ext_vector_type(4)));

// ws layout:
//   [0, 73728)           Bpack: ushort[36][2][64][8]  bf16 B-fragments
//   [73728, 139264)      part:  float[256][64]
//   [204800, 8593424)    Xb:    uint4[524289]  per-input-pixel basis (8 bf16)
//                        slot 524288 = basis(0) for padding redirect
#define PART_OFF 73728
#define XB_OFF   204800
#define XB_CONST 524288

__device__ __forceinline__ unsigned int pack2bf(float a, float b) {
    unsigned int ua = __float_as_uint(a) + 0x8000u;
    unsigned int ub = __float_as_uint(b) + 0x8000u;
    return __builtin_amdgcn_perm(ub, ua, 0x07060302u);   // {hi16(ub),hi16(ua)}
}

__device__ __forceinline__ uint4 basis8(float pv) {
    constexpr float A_S = 2.1019642153762871f;   // sqrt(log2 e) * 7/4
    float e[G_];
#pragma unroll
    for (int g = 0; g < G_; ++g) {
        float gv = -2.0f + (float)g * (4.0f / 7.0f);
        float r  = fmaf(pv, A_S, -gv * A_S);
        e[g] = __builtin_amdgcn_exp2f(-(r * r));
    }
    uint4 au;
    au.x = pack2bf(e[0], e[1]);
    au.y = pack2bf(e[2], e[3]);
    au.z = pack2bf(e[4], e[5]);
    au.w = pack2bf(e[6], e[7]);
    return au;
}

// ---------- prep ----------
// blocks 0-287: Wsum -> B-frags, 8-way d-split (18 loads/thread, 1152 waves).
//   s = {lane bits 4-5} + 4*(wave&1); pairhalf = wave>>1. Coalesced: each
//   16-lane group reads 16 consecutive float4 (256B segment).
//   Combine: shfl_xor(16|32) in-wave (4 s's), then LDS add across wave pair.
// blocks 288-799: basis, 4 px/thread via float4 x loads.
__global__ void __launch_bounds__(256)
prep_kernel(const float* __restrict__ W, const float* __restrict__ x,
            unsigned short* __restrict__ Bpack, uint4* __restrict__ Xb) {
    int bid = blockIdx.x;
    if (bid < 288) {
        __shared__ float4 xw[2][16];         // odd-wave partials
        int tid  = threadIdx.x;
        int k4lo = tid & 15;
        int wvid = tid >> 6;                 // 0..3
        int s    = ((tid >> 4) & 3) | ((wvid & 1) << 2);   // 0..7
        int ph   = wvid >> 1;                // pair-half 0..1
        int pairid = bid * 32 + ph * 16 + k4lo;            // 9216 (o,k4) pairs
        int o  = pairid / 288;
        int k4 = pairid - o * 288;
        const float4* p = reinterpret_cast<const float4*>(
            W + (size_t)o * (D_ * KDIM_) + (size_t)(s * 18) * KDIM_) + k4;
        float4 a = make_float4(0.f, 0.f, 0.f, 0.f);
#pragma unroll
        for (int dd = 0; dd < 18; ++dd) {
            float4 v = p[dd * (KDIM_ / 4)];
            a.x += v.x; a.y += v.y; a.z += v.z; a.w += v.w;
        }
        a.x += __shfl_xor(a.x, 16); a.y += __shfl_xor(a.y, 16);
        a.z += __shfl_xor(a.z, 16); a.w += __shfl_xor(a.w, 16);
        a.x += __shfl_xor(a.x, 32); a.y += __shfl_xor(a.y, 32);
        a.z += __shfl_xor(a.z, 32); a.w += __shfl_xor(a.w, 32);
        if ((wvid & 1) == 1 && k4lo == (tid & 63) % 16 && (tid & 63) < 16)
            xw[ph][k4lo] = make_float4(a.x, a.y, a.z, a.w);
        __syncthreads();
        if ((wvid & 1) == 0 && (tid & 63) < 16) {
            float4 b4 = xw[ph][k4lo];
            float v[4] = {a.x + b4.x, a.y + b4.y, a.z + b4.z, a.w + b4.w};
            ushort4v hb;
#pragma unroll
            for (int j = 0; j < 4; ++j) {
                unsigned int u = __float_as_uint(v[j]);
                u += 0x7FFFu + ((u >> 16) & 1u);          // RNE to bf16
                hb[j] = (unsigned short)(u >> 16);
            }
            int k  = k4 * 4;
            int kc = k >> 5;
            int lane_ = (((k >> 3) & 3) << 4) | (o & 15);
            int hh = o >> 4, e = k & 7;
            *reinterpret_cast<ushort4v*>(
                &Bpack[(((kc * 2 + hh) * 64) + lane_) * 8 + e]) = hb;
        }
    } else {
        int pi4 = (bid - 288) * 256 + threadIdx.x;   // 131072 quads
        float4 xv = reinterpret_cast<const float4*>(x)[pi4];
        uint4* dst = Xb + (size_t)pi4 * 4;
        dst[0] = basis8(xv.x);
        dst[1] = basis8(xv.y);
        dst[2] = basis8(xv.z);
        dst[3] = basis8(xv.w);
        if (pi4 == 0) Xb[XB_CONST] = basis8(0.0f);   // padding constant
    }
}

// ---------- main: MFMA GEMM; 512 thr (8 waves) -> 4 waves/SIMD ----------
// T1 XCD swizzle: vb = ((bid&7)<<5)|(bid>>3) -> XCD k owns batch k (L2-fit).
__global__ void __launch_bounds__(512, 2)
main_kernel(const uint4* __restrict__ Xb, const uint4* __restrict__ Bpackv,
            float* __restrict__ out, float* __restrict__ part) {
    __shared__ uint4 Bsh[KC_ * 2 * 64];          // 73728 B; reused for reduce

#pragma unroll
    for (int i = 0; i < 9; ++i) {
        int idx = threadIdx.x + i * 512;
        Bsh[idx] = Bpackv[idx];
    }

    int vb   = ((blockIdx.x & 7) << 5) | (blockIdx.x >> 3);   // XCD-local
    int tid  = threadIdx.x;
    int l    = tid & 63;
    int wv   = tid >> 6;         // 0..7
    int m    = l & 15;
    int hi   = l >> 4;
    int pixbase = vb * 128 + wv * 16;
    int n    = pixbase + m;
    int b    = n >> 12;
    int y    = (n >> 6) & 63;
    int xc   = n & 63;

    // prologue: 36 A-frag indices (OOB -> basis(0) slot)
    int off[KC_];
#pragma unroll
    for (int kc = 0; kc < KC_; ++kc) {
        int d  = kc * 4 + hi;
        int c  = (d * 57) >> 9;          // d/9
        int r9 = d - c * 9;
        int kh = (r9 * 11) >> 5;         // r9/3
        int kw = r9 - kh * 3;
        int iy = y + kh - 1;
        int ix = xc + kw - 1;
        bool valid = ((unsigned)iy < 64u) & ((unsigned)ix < 64u);
        int pix = ((b * 16 + c) << 12) + (iy << 6) + ix;
        off[kc] = valid ? pix : XB_CONST;
    }
    __syncthreads();                     // B staged

    f32x4 acc0 = {0.f, 0.f, 0.f, 0.f};
    f32x4 acc1 = {0.f, 0.f, 0.f, 0.f};

#pragma unroll
    for (int kc = 0; kc < KC_; ++kc) {
        uint4 au = Xb[off[kc]];
        short8v afrag = __builtin_bit_cast(short8v, au);
        short8v b0 = __builtin_bit_cast(short8v, Bsh[(kc * 2 + 0) * 64 + l]);
        short8v b1 = __builtin_bit_cast(short8v, Bsh[(kc * 2 + 1) * 64 + l]);
        acc0 = __builtin_amdgcn_mfma_f32_16x16x32_bf16(afrag, b0, acc0, 0, 0, 0);
        acc1 = __builtin_amdgcn_mfma_f32_16x16x32_bf16(afrag, b1, acc1, 0, 0, 0);
    }

    // store raw GEMM result
    int prp = (pixbase & 4095) + hi * 4;
    float* dst0 = out + (((size_t)(b * O_ + m)) << 12) + prp;
    float* dst1 = out + (((size_t)(b * O_ + m + 16)) << 12) + prp;
    *reinterpret_cast<f32x4*>(dst0) = acc0;
    *reinterpret_cast<f32x4*>(dst1) = acc1;

    // BN partials from registers
    float s0 = acc0.x + acc0.y + acc0.z + acc0.w;
    float q0 = acc0.x*acc0.x + acc0.y*acc0.y + acc0.z*acc0.z + acc0.w*acc0.w;
    float s1 = acc1.x + acc1.y + acc1.z + acc1.w;
    float q1 = acc1.x*acc1.x + acc1.y*acc1.y + acc1.z*acc1.z + acc1.w*acc1.w;
    s0 += __shfl_xor(s0, 16); s0 += __shfl_xor(s0, 32);
    q0 += __shfl_xor(q0, 16); q0 += __shfl_xor(q0, 32);
    s1 += __shfl_xor(s1, 16); s1 += __shfl_xor(s1, 32);
    q1 += __shfl_xor(q1, 16); q1 += __shfl_xor(q1, 32);

    float* red = (float*)Bsh;
    __syncthreads();                     // done reading Bsh
    if (l < 16) {
        red[wv * 64 +      m] = s0;
        red[wv * 64 + 16 + m] = s1;
        red[wv * 64 + 32 + m] = q0;
        red[wv * 64 + 48 + m] = q1;
    }
    __syncthreads();
    if (tid < 64) {
        float v = 0.f;
#pragma unroll
        for (int w = 0; w < 8; ++w) v += red[w * 64 + tid];
        part[vb * 64 + tid] = v;
    }
}

// ---------- BN apply: column-only stat reduce (256 rows) ----------
__global__ void __launch_bounds__(256)
bn_apply(float* __restrict__ out, const float* __restrict__ part,
         const float* __restrict__ gamma, const float* __restrict__ beta) {
    __shared__ float ws[8];
    int tid = threadIdx.x;
    int o   = blockIdx.x & 31;

    float s = part[tid * 64 + o];
    float q = part[tid * 64 + 32 + o];
#pragma unroll
    for (int off = 32; off > 0; off >>= 1) {
        s += __shfl_down(s, off);
        q += __shfl_down(q, off);
    }
    int wvid = tid >> 6;
    if ((tid & 63) == 0) { ws[wvid] = s; ws[4 + wvid] = q; }
    __syncthreads();
    float S = ws[0] + ws[1] + ws[2] + ws[3];
    float Q = ws[4] + ws[5] + ws[6] + ws[7];

    float mean = S * (1.f / (float)NPIX_);
    float var  = Q * (1.f / (float)NPIX_) - mean * mean;
    float rstd = rsqrtf(var + 1e-5f);
    float sc   = gamma[o] * rstd;
    float sh   = beta[o] - mean * sc;

    float4* f4 = reinterpret_cast<float4*>(out) + (size_t)blockIdx.x * 1024;
#pragma unroll
    for (int j = 0; j < 4; ++j) {
        float4 v = f4[tid + j * 256];
        v.x = v.x * sc + sh; v.y = v.y * sc + sh;
        v.z = v.z * sc + sh; v.w = v.w * sc + sh;
        f4[tid + j * 256] = v;
    }
}

extern "C" void kernel_launch(void* const* d_in, const int* in_sizes, int n_in,
                              void* d_out, int out_size, void* d_ws, size_t ws_size,
                              hipStream_t stream) {
    const float* x     = (const float*)d_in[0];
    const float* W     = (const float*)d_in[1];
    const float* gamma = (const float*)d_in[2];
    const float* beta  = (const float*)d_in[3];
    float* out = (float*)d_out;
    unsigned short* Bpack = (unsigned short*)d_ws;
    float* part = (float*)((char*)d_ws + PART_OFF);
    uint4* Xb   = (uint4*)((char*)d_ws + XB_OFF);

    hipLaunchKernelGGL(prep_kernel, dim3(288 + 512), dim3(256), 0, stream,
                       W, x, Bpack, Xb);
    hipLaunchKernelGGL(main_kernel, dim3(NMAIN_), dim3(512), 0, stream,
                       Xb, (const uint4*)Bpack, out, part);
    hipLaunchKernelGGL(bn_apply, dim3(256), dim3(256), 0, stream,
                       out, part, gamma, beta);
}